// Round 4
// baseline (1073.720 us; speedup 1.0000x reference)
//
#include <hip/hip_runtime.h>

// ---------------------------------------------------------------------------
// DyHetGNN forward, fused: slots -> gather -> ONE mega kernel per 64-row tile
// running the whole 14-GEMM chain with LDS/register intermediates.
// Slots: etype0 rows [0,cnt0), etype1 rows [S_TOP-cnt1, S_TOP); pads garbage.
// ---------------------------------------------------------------------------

#define M_EDGES 32768
#define S_TOP   32896          // M + 128, multiple of 128 (and of 64)
#define TROWS   64
#define GRID_MEGA (S_TOP / TROWS)   // 514

typedef __bf16 bf16_t;
typedef __bf16 bf16x8 __attribute__((ext_vector_type(8)));
typedef float  f32x4  __attribute__((ext_vector_type(4)));

// weight buffer segment offsets (bf16 elements), all stored [n][k] (k=256 contig)
#define OFF_W1ST 0
#define OFF_W2ST 131072
#define OFF_W1GT 262144
#define OFF_W2GT 393216
#define OFF_WST  524288
#define OFF_WGT  589824
#define OFF_WXT  655360
#define OFF_WHT  917504
#define WBUF_ELEMS 1179648

__device__ __forceinline__ float sigm_f(float x) { return 1.f / (1.f + __expf(-x)); }
__device__ __forceinline__ float tanh_f(float x) {
  x = fminf(fmaxf(x, -15.f), 15.f);
  float e = __expf(2.f * x);
  return (e - 1.f) / (e + 1.f);
}

// ---------------- prep: weight transpose/cast + array init ----------------
__global__ __launch_bounds__(256)
void k_init(const float* __restrict__ W1s, const float* __restrict__ W2s,
            const float* __restrict__ W1g, const float* __restrict__ W2g,
            const float* __restrict__ Wsw, const float* __restrict__ Wgw,
            const float* __restrict__ Wx,  const float* __restrict__ Wh,
            bf16_t* __restrict__ wbuf, int* __restrict__ eid,
            int* __restrict__ srcn, int* __restrict__ dstn,
            float* __restrict__ dts, int* __restrict__ cnt)
{
  const int b = blockIdx.x, tid = threadIdx.x;
  if (b < 256) {                       // 64x64 transpose tiles, fp32 -> bf16
    const float* src; bf16_t* dst; int C_in, n0, k0;
    if (b < 128) {
      const int grp = b >> 5, e = (b >> 4) & 1, t16 = b & 15;
      const float* bases[4] = {W1s, W2s, W1g, W2g};
      src = bases[grp] + e * 65536;
      dst = wbuf + grp * 131072 + e * 65536;
      C_in = 256; n0 = (t16 >> 2) * 64; k0 = (t16 & 3) * 64;
    } else {
      const int b2 = b - 128, mat = b2 >> 6, t64 = b2 & 63;
      src = mat ? Wh : Wx;
      dst = wbuf + OFF_WXT + mat * 262144;
      C_in = 1024; n0 = (t64 >> 2) * 64; k0 = (t64 & 3) * 64;
    }
    __shared__ float tile[64][65];
    const int r = tid >> 2, cg = (tid & 3) * 16;
#pragma unroll
    for (int j = 0; j < 4; ++j) {
      float4 v = *(const float4*)(src + (k0 + r) * C_in + n0 + cg + 4 * j);
      tile[r][cg + 4 * j + 0] = v.x;
      tile[r][cg + 4 * j + 1] = v.y;
      tile[r][cg + 4 * j + 2] = v.z;
      tile[r][cg + 4 * j + 3] = v.w;
    }
    __syncthreads();
    const int c2 = tid >> 2, rg = (tid & 3) * 16;
#pragma unroll
    for (int j = 0; j < 16; ++j)
      dst[(n0 + c2) * 256 + k0 + rg + j] = (bf16_t)tile[rg + j][c2];
  } else {                             // plain casts + defaults
    const int idx0 = (b - 256) * 256 + tid;
    for (int i = idx0; i < 65536; i += 32768) {
      wbuf[OFF_WST + i] = (bf16_t)Wsw[i];   // Ws_w used transposed -> direct cast
      wbuf[OFF_WGT + i] = (bf16_t)Wgw[i];
    }
    for (int i = idx0; i < S_TOP; i += 32768) {
      eid[i] = -1; srcn[i] = 0; dstn[i] = 0; dts[i] = 0.f;
    }
    if (idx0 < 2) cnt[idx0] = 0;
  }
}

// ---------------- slot assignment (wave-aggregated atomics) ----------------
__global__ __launch_bounds__(256)
void k_slots(const int* __restrict__ etype, const int* __restrict__ src,
             const int* __restrict__ dst, const float* __restrict__ dt,
             int* __restrict__ cnt, int* __restrict__ eid, int* __restrict__ srcn,
             int* __restrict__ dstn, float* __restrict__ dts)
{
  const int m = blockIdx.x * 256 + threadIdx.x;
  const int lane = threadIdx.x & 63;
  const int e = etype[m];
  const unsigned long long b0 = __ballot(e == 0);
  const unsigned long long lt = (1ull << lane) - 1;
  const int c0 = __popcll(b0);
  int a0 = 0, a1 = 0;
  if (lane == 0) {
    a0 = atomicAdd(&cnt[0], c0);
    a1 = atomicAdd(&cnt[1], 64 - c0);
  }
  a0 = __shfl(a0, 0);
  a1 = __shfl(a1, 0);
  const int pos = (e == 0) ? (a0 + __popcll(b0 & lt))
                           : (a1 + __popcll(~b0 & lt));
  const int s = (e == 0) ? pos : (S_TOP - 1 - pos);
  eid[s] = m; srcn[s] = src[m]; dstn[s] = dst[m]; dts[s] = dt[m];
}

// ---------------- gather hid rows -> bf16 slot-ordered ----------------
__global__ __launch_bounds__(256)
void k_gather(const float* __restrict__ hid, const int* __restrict__ srcn,
              const int* __restrict__ dstn, bf16_t* __restrict__ Xs,
              bf16_t* __restrict__ Xg)
{
  const int s = blockIdx.x * 4 + (threadIdx.x >> 6);
  const int c = (threadIdx.x & 63) * 4;
  const int ns = srcn[s], ng = dstn[s];
  float4 vs = *(const float4*)(hid + (size_t)ns * 256 + c);
  float4 vg = *(const float4*)(hid + (size_t)ng * 256 + c);
  union { bf16_t h[4]; unsigned long long u; } pk;
  pk.h[0] = (bf16_t)vs.x; pk.h[1] = (bf16_t)vs.y; pk.h[2] = (bf16_t)vs.z; pk.h[3] = (bf16_t)vs.w;
  *(unsigned long long*)(Xs + s * 256 + c) = pk.u;
  pk.h[0] = (bf16_t)vg.x; pk.h[1] = (bf16_t)vg.y; pk.h[2] = (bf16_t)vg.z; pk.h[3] = (bf16_t)vg.w;
  *(unsigned long long*)(Xg + s * 256 + c) = pk.u;
}

// ---------------- mega-kernel helpers ----------------
__device__ __forceinline__ bf16x8 gfrag(const bf16_t* b, int row, int k) {
  return *(const bf16x8*)(b + (size_t)row * 256 + k);
}
// LDS tile [64][256] bf16, row stride 512B, XOR-swizzled within row (16B units)
__device__ __forceinline__ bf16x8 lfrag(const unsigned short* buf, int row, int kbyte) {
  return *(const bf16x8*)((const char*)buf + row * 512 + (kbyte ^ ((row & 7) << 4)));
}
__device__ __forceinline__ void lstore(unsigned short* buf, int row, int colbyte, bf16_t v) {
  *(bf16_t*)((char*)buf + row * 512 + (colbyte ^ ((row & 7) << 4))) = v;
}
__device__ __forceinline__ void zacc(f32x4 (&acc)[4][4]) {
  const f32x4 z = {0.f, 0.f, 0.f, 0.f};
#pragma unroll
  for (int a = 0; a < 4; ++a)
#pragma unroll
    for (int b = 0; b < 4; ++b) acc[a][b] = z;
}
// one K=256 GEMM-accumulate over a 64-row tile; this wave's 64-col slab.
// A from LDS tile (LDSA) or global row-major [.,256] bf16; W stored [n][k].
template<bool LDSA>
__device__ __forceinline__ void gacc(f32x4 (&acc)[4][4], const unsigned short* lb,
                                     const bf16_t* gA, int grow0,
                                     const bf16_t* W, int w, int lo, int hi)
{
#pragma unroll
  for (int c = 0; c < 4; ++c)
#pragma unroll
    for (int ks = 0; ks < 2; ++ks) {
      const int k = c * 64 + ks * 32 + hi * 8;
      bf16x8 af[4];
#pragma unroll
      for (int rb = 0; rb < 4; ++rb) {
        if constexpr (LDSA) af[rb] = lfrag(lb, rb * 16 + lo, k * 2);
        else                af[rb] = gfrag(gA, grow0 + rb * 16 + lo, k);
      }
#pragma unroll
      for (int tc = 0; tc < 4; ++tc) {
        bf16x8 bfv = gfrag(W, w * 64 + tc * 16 + lo, k);
#pragma unroll
        for (int rb = 0; rb < 4; ++rb)
          acc[rb][tc] = __builtin_amdgcn_mfma_f32_16x16x32_bf16(af[rb], bfv, acc[rb][tc], 0, 0, 0);
      }
    }
}

// ---------------- the fused chain kernel ----------------
__global__ __launch_bounds__(256, 2)
void k_mega(const bf16_t* __restrict__ Xs, const bf16_t* __restrict__ Xg,
            const bf16_t* __restrict__ wbuf,
            const float* __restrict__ b1s, const float* __restrict__ b2s,
            const float* __restrict__ b1g, const float* __restrict__ b2g,
            const float* __restrict__ p_w, const float* __restrict__ p_b,
            const float* __restrict__ q_w, const float* __restrict__ q_b,
            const float* __restrict__ Wsb, const float* __restrict__ Wgb,
            const float* __restrict__ b_lstm, const float* __restrict__ w_out,
            const float* __restrict__ b_out, const float* __restrict__ decay_w,
            const float* __restrict__ cell, const int* __restrict__ cnt,
            const int* __restrict__ eid, const int* __restrict__ dstn,
            const float* __restrict__ dts,
            float* __restrict__ outS, float* __restrict__ outH, float* __restrict__ outC)
{
  const int tid = threadIdx.x;
  const int w = tid >> 6, lane = tid & 63, lo = lane & 15, hi = lane >> 4;
  const int row0 = blockIdx.x * TROWS;
  const int cnt0 = cnt[0], cnt1 = cnt[1];
  const int cnt0r = (cnt0 + TROWS - 1) & ~(TROWS - 1);
  const int v1 = S_TOP - cnt1;
  if (row0 >= cnt0r && row0 + TROWS <= v1) return;   // fully-dead block
  const int e = (row0 < cnt0r) ? 0 : 1;

  __shared__ unsigned short bufA[TROWS * 256];   // 32 KiB ping
  __shared__ unsigned short bufB[TROWS * 256];   // 32 KiB pong
  __shared__ float ps[TROWS], qs[TROWS], aa[TROWS], sdot[TROWS], decv[TROWS];
  __shared__ int leid[TROWS], lnd[TROWS];

  if (tid < TROWS) {
    const int r = row0 + tid;
    ps[tid] = 0.f; qs[tid] = 0.f; sdot[tid] = 0.f;
    leid[tid] = eid[r]; lnd[tid] = dstn[r];
    decv[tid] = __expf(-fabsf(decay_w[0]) * dts[r]);
  }

  f32x4 acc[4][4];

  // ---- P1: h1s = relu(Xs @ W1s[e] + b1s[e]) -> bufA
  zacc(acc);
  gacc<false>(acc, nullptr, Xs, row0, wbuf + OFF_W1ST + e * 65536, w, lo, hi);
  {
    const float* bias = b1s + e * 256;
#pragma unroll
    for (int tc = 0; tc < 4; ++tc) {
      const int col = w * 64 + tc * 16 + lo;
      const float bs = bias[col];
#pragma unroll
      for (int rb = 0; rb < 4; ++rb)
#pragma unroll
        for (int i = 0; i < 4; ++i)
          lstore(bufA, rb * 16 + hi * 4 + i, col * 2, (bf16_t)fmaxf(acc[rb][tc][i] + bs, 0.f));
    }
  }
  __syncthreads();

  // ---- P2: msg_s = bufA @ W2s[e] + b2s[e] -> bufB ; ps += msg_s . p_w
  zacc(acc);
  gacc<true>(acc, bufA, nullptr, 0, wbuf + OFF_W2ST + e * 65536, w, lo, hi);
  {
    const float* bias = b2s + e * 256;
    float dp[4][4] = {};
#pragma unroll
    for (int tc = 0; tc < 4; ++tc) {
      const int col = w * 64 + tc * 16 + lo;
      const float bs = bias[col], pw = p_w[col];
#pragma unroll
      for (int rb = 0; rb < 4; ++rb)
#pragma unroll
        for (int i = 0; i < 4; ++i) {
          const float v = acc[rb][tc][i] + bs;
          lstore(bufB, rb * 16 + hi * 4 + i, col * 2, (bf16_t)v);
          dp[rb][i] += v * pw;
        }
    }
#pragma unroll
    for (int rb = 0; rb < 4; ++rb)
#pragma unroll
      for (int i = 0; i < 4; ++i) {
        float d = dp[rb][i];
        d += __shfl_xor(d, 1); d += __shfl_xor(d, 2);
        d += __shfl_xor(d, 4); d += __shfl_xor(d, 8);
        if (lo == 0) atomicAdd(&ps[rb * 16 + hi * 4 + i], d);
      }
  }
  __syncthreads();

  // ---- P3: T = bufB @ Ws^T + Ws_b -> registers (f32)
  f32x4 T[4][4];
  zacc(acc);
  gacc<true>(acc, bufB, nullptr, 0, wbuf + OFF_WST, w, lo, hi);
#pragma unroll
  for (int tc = 0; tc < 4; ++tc) {
    const float bs = Wsb[w * 64 + tc * 16 + lo];
#pragma unroll
    for (int rb = 0; rb < 4; ++rb)
#pragma unroll
      for (int i = 0; i < 4; ++i) T[rb][tc][i] = acc[rb][tc][i] + bs;
  }

  // ---- P4: h1g = relu(Xg @ W1g[e] + b1g[e]) -> bufA
  zacc(acc);
  gacc<false>(acc, nullptr, Xg, row0, wbuf + OFF_W1GT + e * 65536, w, lo, hi);
  {
    const float* bias = b1g + e * 256;
#pragma unroll
    for (int tc = 0; tc < 4; ++tc) {
      const int col = w * 64 + tc * 16 + lo;
      const float bs = bias[col];
#pragma unroll
      for (int rb = 0; rb < 4; ++rb)
#pragma unroll
        for (int i = 0; i < 4; ++i)
          lstore(bufA, rb * 16 + hi * 4 + i, col * 2, (bf16_t)fmaxf(acc[rb][tc][i] + bs, 0.f));
    }
  }
  __syncthreads();

  // ---- P5: msg_g = bufA @ W2g[e] + b2g[e] -> bufB ; qs += msg_g . q_w
  zacc(acc);
  gacc<true>(acc, bufA, nullptr, 0, wbuf + OFF_W2GT + e * 65536, w, lo, hi);
  {
    const float* bias = b2g + e * 256;
    float dp[4][4] = {};
#pragma unroll
    for (int tc = 0; tc < 4; ++tc) {
      const int col = w * 64 + tc * 16 + lo;
      const float bs = bias[col], qw = q_w[col];
#pragma unroll
      for (int rb = 0; rb < 4; ++rb)
#pragma unroll
        for (int i = 0; i < 4; ++i) {
          const float v = acc[rb][tc][i] + bs;
          lstore(bufB, rb * 16 + hi * 4 + i, col * 2, (bf16_t)v);
          dp[rb][i] += v * qw;
        }
    }
#pragma unroll
    for (int rb = 0; rb < 4; ++rb)
#pragma unroll
      for (int i = 0; i < 4; ++i) {
        float d = dp[rb][i];
        d += __shfl_xor(d, 1); d += __shfl_xor(d, 2);
        d += __shfl_xor(d, 4); d += __shfl_xor(d, 8);
        if (lo == 0) atomicAdd(&qs[rb * 16 + hi * 4 + i], d);
      }
  }
  __syncthreads();

  // ---- a = sigmoid(ps + qs + p_b + q_b)
  if (tid < TROWS) aa[tid] = sigm_f(ps[tid] + qs[tid] + p_b[0] + q_b[0]);
  __syncthreads();

  // ---- P6: G = bufB @ Wg^T + Wg_b ; X = a*T + (1-a)*G -> bufA
  zacc(acc);
  gacc<true>(acc, bufB, nullptr, 0, wbuf + OFF_WGT, w, lo, hi);
#pragma unroll
  for (int tc = 0; tc < 4; ++tc) {
    const int col = w * 64 + tc * 16 + lo;
    const float bs = Wgb[col];
#pragma unroll
    for (int rb = 0; rb < 4; ++rb)
#pragma unroll
      for (int i = 0; i < 4; ++i) {
        const int ri = rb * 16 + hi * 4 + i;
        const float av = aa[ri];
        const float x = av * T[rb][tc][i] + (1.f - av) * (acc[rb][tc][i] + bs);
        lstore(bufA, ri, col * 2, (bf16_t)x);
      }
  }
  __syncthreads();

  // ---- gates: acc_G = bufA @ Wx_G + Xg @ Wh_G + b_lstm_G, order g,i,f,o
  f32x4 carry[4][4];
  // gate 2 ("g"): carry = tanh(pre)
  zacc(acc);
  gacc<true >(acc, bufA, nullptr, 0, wbuf + OFF_WXT + 2 * 65536, w, lo, hi);
  gacc<false>(acc, nullptr, Xg, row0, wbuf + OFF_WHT + 2 * 65536, w, lo, hi);
#pragma unroll
  for (int tc = 0; tc < 4; ++tc) {
    const float bs = b_lstm[2 * 256 + w * 64 + tc * 16 + lo];
#pragma unroll
    for (int rb = 0; rb < 4; ++rb)
#pragma unroll
      for (int i = 0; i < 4; ++i) carry[rb][tc][i] = tanh_f(acc[rb][tc][i] + bs);
  }
  // gate 0 ("i"): carry = sigm(pre) * carry
  zacc(acc);
  gacc<true >(acc, bufA, nullptr, 0, wbuf + OFF_WXT + 0 * 65536, w, lo, hi);
  gacc<false>(acc, nullptr, Xg, row0, wbuf + OFF_WHT + 0 * 65536, w, lo, hi);
#pragma unroll
  for (int tc = 0; tc < 4; ++tc) {
    const float bs = b_lstm[0 * 256 + w * 64 + tc * 16 + lo];
#pragma unroll
    for (int rb = 0; rb < 4; ++rb)
#pragma unroll
      for (int i = 0; i < 4; ++i) carry[rb][tc][i] *= sigm_f(acc[rb][tc][i] + bs);
  }
  // gate 1 ("f"): carry += sigm(pre) * c_dec
  zacc(acc);
  gacc<true >(acc, bufA, nullptr, 0, wbuf + OFF_WXT + 1 * 65536, w, lo, hi);
  gacc<false>(acc, nullptr, Xg, row0, wbuf + OFF_WHT + 1 * 65536, w, lo, hi);
#pragma unroll
  for (int tc = 0; tc < 4; ++tc) {
    const int col = w * 64 + tc * 16 + lo;
    const float bs = b_lstm[1 * 256 + col];
#pragma unroll
    for (int rb = 0; rb < 4; ++rb)
#pragma unroll
      for (int i = 0; i < 4; ++i) {
        const int ri = rb * 16 + hi * 4 + i;
        const float cdec = cell[(size_t)lnd[ri] * 256 + col] * decv[ri];
        carry[rb][tc][i] += sigm_f(acc[rb][tc][i] + bs) * cdec;
      }
  }
  // gate 3 ("o"): c_new = carry; h = sigm(pre)*tanh(c_new); outputs + score dot
  zacc(acc);
  gacc<true >(acc, bufA, nullptr, 0, wbuf + OFF_WXT + 3 * 65536, w, lo, hi);
  gacc<false>(acc, nullptr, Xg, row0, wbuf + OFF_WHT + 3 * 65536, w, lo, hi);
  {
    float dp[4][4] = {};
#pragma unroll
    for (int tc = 0; tc < 4; ++tc) {
      const int col = w * 64 + tc * 16 + lo;
      const float bs = b_lstm[3 * 256 + col];
      const float wo = w_out[col];
#pragma unroll
      for (int rb = 0; rb < 4; ++rb)
#pragma unroll
        for (int i = 0; i < 4; ++i) {
          const int ri = rb * 16 + hi * 4 + i;
          const int m = leid[ri];
          const float cn = carry[rb][tc][i];
          const float hn = sigm_f(acc[rb][tc][i] + bs) * tanh_f(cn);
          if (m >= 0) {
            outH[(size_t)m * 256 + col] = hn;
            outC[(size_t)m * 256 + col] = cn;
          }
          dp[rb][i] += hn * wo;
        }
    }
#pragma unroll
    for (int rb = 0; rb < 4; ++rb)
#pragma unroll
      for (int i = 0; i < 4; ++i) {
        float d = dp[rb][i];
        d += __shfl_xor(d, 1); d += __shfl_xor(d, 2);
        d += __shfl_xor(d, 4); d += __shfl_xor(d, 8);
        if (lo == 0) atomicAdd(&sdot[rb * 16 + hi * 4 + i], d);
      }
  }
  __syncthreads();
  if (tid < TROWS) {
    const int m = leid[tid];
    if (m >= 0) outS[m] = sigm_f(sdot[tid] + b_out[0]);
  }
}

// ---------------------------------------------------------------------------
extern "C" void kernel_launch(void* const* d_in, const int* in_sizes, int n_in,
                              void* d_out, int out_size, void* d_ws, size_t ws_size,
                              hipStream_t stream)
{
  const int*   src     = (const int*)d_in[0];
  const int*   dst     = (const int*)d_in[1];
  const int*   etype   = (const int*)d_in[2];
  const float* dt      = (const float*)d_in[3];
  const float* hid     = (const float*)d_in[4];
  const float* cell    = (const float*)d_in[5];
  const float* W1s     = (const float*)d_in[6];
  const float* b1s     = (const float*)d_in[7];
  const float* W2s     = (const float*)d_in[8];
  const float* b2s     = (const float*)d_in[9];
  const float* W1g     = (const float*)d_in[10];
  const float* b1g     = (const float*)d_in[11];
  const float* W2g     = (const float*)d_in[12];
  const float* b2g     = (const float*)d_in[13];
  const float* p_w     = (const float*)d_in[14];
  const float* p_b     = (const float*)d_in[15];
  const float* q_w     = (const float*)d_in[16];
  const float* q_b     = (const float*)d_in[17];
  const float* Ws_w    = (const float*)d_in[18];
  const float* Ws_b    = (const float*)d_in[19];
  const float* Wg_w    = (const float*)d_in[20];
  const float* Wg_b    = (const float*)d_in[21];
  const float* Wx      = (const float*)d_in[22];
  const float* Wh      = (const float*)d_in[23];
  const float* b_lstm  = (const float*)d_in[24];
  const float* w_out   = (const float*)d_in[25];
  const float* b_out   = (const float*)d_in[26];
  const float* decay_w = (const float*)d_in[27];
  (void)in_sizes; (void)n_in; (void)out_size; (void)ws_size;

  char* p = (char*)d_ws;
  auto alloc = [&](size_t bytes) { char* r = p; p += (bytes + 255) & ~(size_t)255; return r; };
  const size_t SB = (size_t)S_TOP * 256 * sizeof(bf16_t);
  bf16_t* wbuf = (bf16_t*)alloc(WBUF_ELEMS * sizeof(bf16_t));
  bf16_t* Xs   = (bf16_t*)alloc(SB);
  bf16_t* Xg   = (bf16_t*)alloc(SB);
  int*    eid  = (int*)alloc(S_TOP * 4);
  int*    srcn = (int*)alloc(S_TOP * 4);
  int*    dstn = (int*)alloc(S_TOP * 4);
  float*  dts  = (float*)alloc(S_TOP * 4);
  int*    cnt  = (int*)alloc(256);

  float* outS = (float*)d_out;
  float* outH = outS + M_EDGES;
  float* outC = outH + (size_t)M_EDGES * 256;

  k_init<<<384, 256, 0, stream>>>(W1s, W2s, W1g, W2g, Ws_w, Wg_w, Wx, Wh,
                                  wbuf, eid, srcn, dstn, dts, cnt);
  k_slots<<<M_EDGES / 256, 256, 0, stream>>>(etype, src, dst, dt, cnt, eid, srcn, dstn, dts);
  k_gather<<<S_TOP / 4, 256, 0, stream>>>(hid, srcn, dstn, Xs, Xg);
  k_mega<<<GRID_MEGA, 256, 0, stream>>>(Xs, Xg, wbuf,
      b1s, b2s, b1g, b2g, p_w, p_b, q_w, q_b, Ws_b, Wg_b,
      b_lstm, w_out, b_out, decay_w, cell, cnt, eid, dstn, dts,
      outS, outH, outC);
}

// Round 5
// 699.021 us; speedup vs baseline: 1.5360x; 1.5360x over previous
//
#include <hip/hip_runtime.h>

// ---------------------------------------------------------------------------
// DyHetGNN forward, fused: slots -> gather -> ONE mega kernel per 64-row tile
// running the whole 14-GEMM chain with LDS/register intermediates.
// Register-pressure discipline: only ONE 64-float register array (acc) is ever
// live; T and the LSTM carry live as bf16 in LDS bufB (in-place reuse).
// Slots: etype0 rows [0,cnt0), etype1 rows [S_TOP-cnt1, S_TOP); pads garbage.
// ---------------------------------------------------------------------------

#define M_EDGES 32768
#define S_TOP   32896          // M + 128, multiple of 128 (and of 64)
#define TROWS   64
#define GRID_MEGA (S_TOP / TROWS)   // 514

typedef __bf16 bf16_t;
typedef __bf16 bf16x8 __attribute__((ext_vector_type(8)));
typedef float  f32x4  __attribute__((ext_vector_type(4)));

// weight buffer segment offsets (bf16 elements), all stored [n][k] (k=256 contig)
#define OFF_W1ST 0
#define OFF_W2ST 131072
#define OFF_W1GT 262144
#define OFF_W2GT 393216
#define OFF_WST  524288
#define OFF_WGT  589824
#define OFF_WXT  655360
#define OFF_WHT  917504
#define WBUF_ELEMS 1179648

__device__ __forceinline__ float sigm_f(float x) { return 1.f / (1.f + __expf(-x)); }
__device__ __forceinline__ float tanh_f(float x) {
  x = fminf(fmaxf(x, -15.f), 15.f);
  float e = __expf(2.f * x);
  return (e - 1.f) / (e + 1.f);
}

// ---------------- prep: weight transpose/cast + array init ----------------
__global__ __launch_bounds__(256)
void k_init(const float* __restrict__ W1s, const float* __restrict__ W2s,
            const float* __restrict__ W1g, const float* __restrict__ W2g,
            const float* __restrict__ Wsw, const float* __restrict__ Wgw,
            const float* __restrict__ Wx,  const float* __restrict__ Wh,
            bf16_t* __restrict__ wbuf, int* __restrict__ eid,
            int* __restrict__ srcn, int* __restrict__ dstn,
            float* __restrict__ dts, int* __restrict__ cnt)
{
  const int b = blockIdx.x, tid = threadIdx.x;
  if (b < 256) {                       // 64x64 transpose tiles, fp32 -> bf16
    const float* src; bf16_t* dst; int C_in, n0, k0;
    if (b < 128) {
      const int grp = b >> 5, e = (b >> 4) & 1, t16 = b & 15;
      const float* bases[4] = {W1s, W2s, W1g, W2g};
      src = bases[grp] + e * 65536;
      dst = wbuf + grp * 131072 + e * 65536;
      C_in = 256; n0 = (t16 >> 2) * 64; k0 = (t16 & 3) * 64;
    } else {
      const int b2 = b - 128, mat = b2 >> 6, t64 = b2 & 63;
      src = mat ? Wh : Wx;
      dst = wbuf + OFF_WXT + mat * 262144;
      C_in = 1024; n0 = (t64 >> 2) * 64; k0 = (t64 & 3) * 64;
    }
    __shared__ float tile[64][65];
    const int r = tid >> 2, cg = (tid & 3) * 16;
#pragma unroll
    for (int j = 0; j < 4; ++j) {
      float4 v = *(const float4*)(src + (k0 + r) * C_in + n0 + cg + 4 * j);
      tile[r][cg + 4 * j + 0] = v.x;
      tile[r][cg + 4 * j + 1] = v.y;
      tile[r][cg + 4 * j + 2] = v.z;
      tile[r][cg + 4 * j + 3] = v.w;
    }
    __syncthreads();
    const int c2 = tid >> 2, rg = (tid & 3) * 16;
#pragma unroll
    for (int j = 0; j < 16; ++j)
      dst[(n0 + c2) * 256 + k0 + rg + j] = (bf16_t)tile[rg + j][c2];
  } else {                             // plain casts + defaults
    const int idx0 = (b - 256) * 256 + tid;
    for (int i = idx0; i < 65536; i += 32768) {
      wbuf[OFF_WST + i] = (bf16_t)Wsw[i];   // Ws_w used transposed -> direct cast
      wbuf[OFF_WGT + i] = (bf16_t)Wgw[i];
    }
    for (int i = idx0; i < S_TOP; i += 32768) {
      eid[i] = -1; srcn[i] = 0; dstn[i] = 0; dts[i] = 0.f;
    }
    if (idx0 < 2) cnt[idx0] = 0;
  }
}

// ---------------- slot assignment (wave-aggregated atomics) ----------------
__global__ __launch_bounds__(256)
void k_slots(const int* __restrict__ etype, const int* __restrict__ src,
             const int* __restrict__ dst, const float* __restrict__ dt,
             int* __restrict__ cnt, int* __restrict__ eid, int* __restrict__ srcn,
             int* __restrict__ dstn, float* __restrict__ dts)
{
  const int m = blockIdx.x * 256 + threadIdx.x;
  const int lane = threadIdx.x & 63;
  const int e = etype[m];
  const unsigned long long b0 = __ballot(e == 0);
  const unsigned long long lt = (1ull << lane) - 1;
  const int c0 = __popcll(b0);
  int a0 = 0, a1 = 0;
  if (lane == 0) {
    a0 = atomicAdd(&cnt[0], c0);
    a1 = atomicAdd(&cnt[1], 64 - c0);
  }
  a0 = __shfl(a0, 0);
  a1 = __shfl(a1, 0);
  const int pos = (e == 0) ? (a0 + __popcll(b0 & lt))
                           : (a1 + __popcll(~b0 & lt));
  const int s = (e == 0) ? pos : (S_TOP - 1 - pos);
  eid[s] = m; srcn[s] = src[m]; dstn[s] = dst[m]; dts[s] = dt[m];
}

// ---------------- gather hid rows -> bf16 slot-ordered ----------------
__global__ __launch_bounds__(256)
void k_gather(const float* __restrict__ hid, const int* __restrict__ srcn,
              const int* __restrict__ dstn, bf16_t* __restrict__ Xs,
              bf16_t* __restrict__ Xg)
{
  const int s = blockIdx.x * 4 + (threadIdx.x >> 6);
  const int c = (threadIdx.x & 63) * 4;
  const int ns = srcn[s], ng = dstn[s];
  float4 vs = *(const float4*)(hid + (size_t)ns * 256 + c);
  float4 vg = *(const float4*)(hid + (size_t)ng * 256 + c);
  union { bf16_t h[4]; unsigned long long u; } pk;
  pk.h[0] = (bf16_t)vs.x; pk.h[1] = (bf16_t)vs.y; pk.h[2] = (bf16_t)vs.z; pk.h[3] = (bf16_t)vs.w;
  *(unsigned long long*)(Xs + s * 256 + c) = pk.u;
  pk.h[0] = (bf16_t)vg.x; pk.h[1] = (bf16_t)vg.y; pk.h[2] = (bf16_t)vg.z; pk.h[3] = (bf16_t)vg.w;
  *(unsigned long long*)(Xg + s * 256 + c) = pk.u;
}

// ---------------- mega-kernel helpers ----------------
__device__ __forceinline__ bf16x8 gfrag(const bf16_t* b, int row, int k) {
  return *(const bf16x8*)(b + (size_t)row * 256 + k);
}
// LDS tile [64][256] bf16, row stride 512B, XOR-swizzled within row (16B units)
__device__ __forceinline__ bf16x8 lfrag(const unsigned short* buf, int row, int kbyte) {
  return *(const bf16x8*)((const char*)buf + row * 512 + (kbyte ^ ((row & 7) << 4)));
}
__device__ __forceinline__ void lstore(unsigned short* buf, int row, int colbyte, bf16_t v) {
  *(bf16_t*)((char*)buf + row * 512 + (colbyte ^ ((row & 7) << 4))) = v;
}
__device__ __forceinline__ float lloadf(const unsigned short* buf, int row, int colbyte) {
  return (float)*(const bf16_t*)((const char*)buf + row * 512 + (colbyte ^ ((row & 7) << 4)));
}
__device__ __forceinline__ void zacc(f32x4 (&acc)[4][4]) {
  const f32x4 z = {0.f, 0.f, 0.f, 0.f};
#pragma unroll
  for (int a = 0; a < 4; ++a)
#pragma unroll
    for (int b = 0; b < 4; ++b) acc[a][b] = z;
}
// one K=256 GEMM-accumulate over a 64-row tile; this wave's 64-col slab.
// A from LDS tile (LDSA) or global row-major [.,256] bf16; W stored [n][k].
template<bool LDSA>
__device__ __forceinline__ void gacc(f32x4 (&acc)[4][4], const unsigned short* lb,
                                     const bf16_t* gA, int grow0,
                                     const bf16_t* W, int w, int lo, int hi)
{
#pragma unroll
  for (int c = 0; c < 4; ++c)
#pragma unroll
    for (int ks = 0; ks < 2; ++ks) {
      const int k = c * 64 + ks * 32 + hi * 8;
      bf16x8 af[4];
#pragma unroll
      for (int rb = 0; rb < 4; ++rb) {
        if constexpr (LDSA) af[rb] = lfrag(lb, rb * 16 + lo, k * 2);
        else                af[rb] = gfrag(gA, grow0 + rb * 16 + lo, k);
      }
#pragma unroll
      for (int tc = 0; tc < 4; ++tc) {
        bf16x8 bfv = gfrag(W, w * 64 + tc * 16 + lo, k);
#pragma unroll
        for (int rb = 0; rb < 4; ++rb)
          acc[rb][tc] = __builtin_amdgcn_mfma_f32_16x16x32_bf16(af[rb], bfv, acc[rb][tc], 0, 0, 0);
      }
    }
}

// ---------------- the fused chain kernel ----------------
__global__ __launch_bounds__(256, 2)
void k_mega(const bf16_t* __restrict__ Xs, const bf16_t* __restrict__ Xg,
            const bf16_t* __restrict__ wbuf,
            const float* __restrict__ b1s, const float* __restrict__ b2s,
            const float* __restrict__ b1g, const float* __restrict__ b2g,
            const float* __restrict__ p_w, const float* __restrict__ p_b,
            const float* __restrict__ q_w, const float* __restrict__ q_b,
            const float* __restrict__ Wsb, const float* __restrict__ Wgb,
            const float* __restrict__ b_lstm, const float* __restrict__ w_out,
            const float* __restrict__ b_out, const float* __restrict__ decay_w,
            const float* __restrict__ cell, const int* __restrict__ cnt,
            const int* __restrict__ eid, const int* __restrict__ dstn,
            const float* __restrict__ dts,
            float* __restrict__ outS, float* __restrict__ outH, float* __restrict__ outC)
{
  const int tid = threadIdx.x;
  const int w = tid >> 6, lane = tid & 63, lo = lane & 15, hi = lane >> 4;
  const int row0 = blockIdx.x * TROWS;
  const int cnt0 = cnt[0], cnt1 = cnt[1];
  const int cnt0r = (cnt0 + TROWS - 1) & ~(TROWS - 1);
  const int v1 = S_TOP - cnt1;
  if (row0 >= cnt0r && row0 + TROWS <= v1) return;   // fully-dead block
  const int e = (row0 < cnt0r) ? 0 : 1;

  __shared__ unsigned short bufA[TROWS * 256];   // 32 KiB
  __shared__ unsigned short bufB[TROWS * 256];   // 32 KiB (msg_s -> T -> carry)
  __shared__ float ps[TROWS], qs[TROWS], aa[TROWS], sdot[TROWS], decv[TROWS];
  __shared__ int leid[TROWS], lnd[TROWS];

  if (tid < TROWS) {
    const int r = row0 + tid;
    ps[tid] = 0.f; qs[tid] = 0.f; sdot[tid] = 0.f;
    leid[tid] = eid[r]; lnd[tid] = dstn[r];
    decv[tid] = __expf(-fabsf(decay_w[0]) * dts[r]);
  }

  f32x4 acc[4][4];   // the ONLY 64-float register array ever live

  // ---- P1: h1s = relu(Xs @ W1s[e] + b1s[e]) -> bufA
  zacc(acc);
  gacc<false>(acc, nullptr, Xs, row0, wbuf + OFF_W1ST + e * 65536, w, lo, hi);
  {
    const float* bias = b1s + e * 256;
#pragma unroll
    for (int tc = 0; tc < 4; ++tc) {
      const int col = w * 64 + tc * 16 + lo;
      const float bs = bias[col];
#pragma unroll
      for (int rb = 0; rb < 4; ++rb)
#pragma unroll
        for (int i = 0; i < 4; ++i)
          lstore(bufA, rb * 16 + hi * 4 + i, col * 2, (bf16_t)fmaxf(acc[rb][tc][i] + bs, 0.f));
    }
  }
  __syncthreads();

  // ---- P2: msg_s = bufA @ W2s[e] + b2s[e] -> bufB ; ps += msg_s . p_w
  zacc(acc);
  gacc<true>(acc, bufA, nullptr, 0, wbuf + OFF_W2ST + e * 65536, w, lo, hi);
  {
    const float* bias = b2s + e * 256;
    float dp[4][4] = {};
#pragma unroll
    for (int tc = 0; tc < 4; ++tc) {
      const int col = w * 64 + tc * 16 + lo;
      const float bs = bias[col], pw = p_w[col];
#pragma unroll
      for (int rb = 0; rb < 4; ++rb)
#pragma unroll
        for (int i = 0; i < 4; ++i) {
          const float v = acc[rb][tc][i] + bs;
          lstore(bufB, rb * 16 + hi * 4 + i, col * 2, (bf16_t)v);
          dp[rb][i] += v * pw;
        }
    }
#pragma unroll
    for (int rb = 0; rb < 4; ++rb)
#pragma unroll
      for (int i = 0; i < 4; ++i) {
        float d = dp[rb][i];
        d += __shfl_xor(d, 1); d += __shfl_xor(d, 2);
        d += __shfl_xor(d, 4); d += __shfl_xor(d, 8);
        if (lo == 0) atomicAdd(&ps[rb * 16 + hi * 4 + i], d);
      }
  }
  __syncthreads();

  // ---- P3: T = bufB @ Ws^T + Ws_b  -> stored back IN-PLACE into bufB (bf16)
  zacc(acc);
  gacc<true>(acc, bufB, nullptr, 0, wbuf + OFF_WST, w, lo, hi);
#pragma unroll
  for (int tc = 0; tc < 4; ++tc) {
    const float bs = Wsb[w * 64 + tc * 16 + lo];
#pragma unroll
    for (int rb = 0; rb < 4; ++rb)
#pragma unroll
      for (int i = 0; i < 4; ++i) acc[rb][tc][i] += bs;
  }
  __syncthreads();                      // everyone done READING bufB (msg_s)
#pragma unroll
  for (int tc = 0; tc < 4; ++tc) {
    const int col = w * 64 + tc * 16 + lo;
#pragma unroll
    for (int rb = 0; rb < 4; ++rb)
#pragma unroll
      for (int i = 0; i < 4; ++i)
        lstore(bufB, rb * 16 + hi * 4 + i, col * 2, (bf16_t)acc[rb][tc][i]);
  }
  __syncthreads();

  // ---- P4: h1g = relu(Xg @ W1g[e] + b1g[e]) -> bufA
  zacc(acc);
  gacc<false>(acc, nullptr, Xg, row0, wbuf + OFF_W1GT + e * 65536, w, lo, hi);
  {
    const float* bias = b1g + e * 256;
#pragma unroll
    for (int tc = 0; tc < 4; ++tc) {
      const int col = w * 64 + tc * 16 + lo;
      const float bs = bias[col];
#pragma unroll
      for (int rb = 0; rb < 4; ++rb)
#pragma unroll
        for (int i = 0; i < 4; ++i)
          lstore(bufA, rb * 16 + hi * 4 + i, col * 2, (bf16_t)fmaxf(acc[rb][tc][i] + bs, 0.f));
    }
  }
  __syncthreads();

  // ---- P5: msg_g = bufA @ W2g[e] + b2g[e] -> IN-PLACE into bufA ; qs-dot
  zacc(acc);
  gacc<true>(acc, bufA, nullptr, 0, wbuf + OFF_W2GT + e * 65536, w, lo, hi);
  {
    const float* bias = b2g + e * 256;
    float dp[4][4] = {};
#pragma unroll
    for (int tc = 0; tc < 4; ++tc) {
      const int col = w * 64 + tc * 16 + lo;
      const float bs = bias[col], qw = q_w[col];
#pragma unroll
      for (int rb = 0; rb < 4; ++rb)
#pragma unroll
        for (int i = 0; i < 4; ++i) {
          acc[rb][tc][i] += bs;
          dp[rb][i] += acc[rb][tc][i] * qw;
        }
    }
#pragma unroll
    for (int rb = 0; rb < 4; ++rb)
#pragma unroll
      for (int i = 0; i < 4; ++i) {
        float d = dp[rb][i];
        d += __shfl_xor(d, 1); d += __shfl_xor(d, 2);
        d += __shfl_xor(d, 4); d += __shfl_xor(d, 8);
        if (lo == 0) atomicAdd(&qs[rb * 16 + hi * 4 + i], d);
      }
  }
  __syncthreads();                      // everyone done READING bufA (h1g)
#pragma unroll
  for (int tc = 0; tc < 4; ++tc) {
    const int col = w * 64 + tc * 16 + lo;
#pragma unroll
    for (int rb = 0; rb < 4; ++rb)
#pragma unroll
      for (int i = 0; i < 4; ++i)
        lstore(bufA, rb * 16 + hi * 4 + i, col * 2, (bf16_t)acc[rb][tc][i]);
  }
  __syncthreads();

  // ---- a = sigmoid(ps + qs + p_b + q_b)
  if (tid < TROWS) aa[tid] = sigm_f(ps[tid] + qs[tid] + p_b[0] + q_b[0]);
  __syncthreads();

  // ---- P6: G = bufA @ Wg^T + Wg_b ; X = a*T + (1-a)*G -> IN-PLACE bufA
  zacc(acc);
  gacc<true>(acc, bufA, nullptr, 0, wbuf + OFF_WGT, w, lo, hi);
#pragma unroll
  for (int tc = 0; tc < 4; ++tc) {
    const int col = w * 64 + tc * 16 + lo;
    const float bs = Wgb[col];
#pragma unroll
    for (int rb = 0; rb < 4; ++rb)
#pragma unroll
      for (int i = 0; i < 4; ++i) {
        const int ri = rb * 16 + hi * 4 + i;
        const float av = aa[ri];
        const float tv = lloadf(bufB, ri, col * 2);   // T
        acc[rb][tc][i] = av * tv + (1.f - av) * (acc[rb][tc][i] + bs);
      }
  }
  __syncthreads();                      // reads of bufA (msg_g) + bufB (T) done
#pragma unroll
  for (int tc = 0; tc < 4; ++tc) {
    const int col = w * 64 + tc * 16 + lo;
#pragma unroll
    for (int rb = 0; rb < 4; ++rb)
#pragma unroll
      for (int i = 0; i < 4; ++i)
        lstore(bufA, rb * 16 + hi * 4 + i, col * 2, (bf16_t)acc[rb][tc][i]);
  }
  __syncthreads();

  // ---- gates (X = bufA stays pinned; carry lives bf16 in bufB, thread-private
  //      elementwise slots -> no barriers needed between gates).
  // gate "g": carry = tanh(pre)
  zacc(acc);
  gacc<true >(acc, bufA, nullptr, 0, wbuf + OFF_WXT + 2 * 65536, w, lo, hi);
  gacc<false>(acc, nullptr, Xg, row0, wbuf + OFF_WHT + 2 * 65536, w, lo, hi);
#pragma unroll
  for (int tc = 0; tc < 4; ++tc) {
    const int col = w * 64 + tc * 16 + lo;
    const float bs = b_lstm[2 * 256 + col];
#pragma unroll
    for (int rb = 0; rb < 4; ++rb)
#pragma unroll
      for (int i = 0; i < 4; ++i)
        lstore(bufB, rb * 16 + hi * 4 + i, col * 2, (bf16_t)tanh_f(acc[rb][tc][i] + bs));
  }
  // gate "i": carry *= sigm(pre)
  zacc(acc);
  gacc<true >(acc, bufA, nullptr, 0, wbuf + OFF_WXT + 0 * 65536, w, lo, hi);
  gacc<false>(acc, nullptr, Xg, row0, wbuf + OFF_WHT + 0 * 65536, w, lo, hi);
#pragma unroll
  for (int tc = 0; tc < 4; ++tc) {
    const int col = w * 64 + tc * 16 + lo;
    const float bs = b_lstm[0 * 256 + col];
#pragma unroll
    for (int rb = 0; rb < 4; ++rb)
#pragma unroll
      for (int i = 0; i < 4; ++i) {
        const int ri = rb * 16 + hi * 4 + i;
        const float c1 = lloadf(bufB, ri, col * 2) * sigm_f(acc[rb][tc][i] + bs);
        lstore(bufB, ri, col * 2, (bf16_t)c1);
      }
  }
  // gate "f": carry += sigm(pre) * c_dec
  zacc(acc);
  gacc<true >(acc, bufA, nullptr, 0, wbuf + OFF_WXT + 1 * 65536, w, lo, hi);
  gacc<false>(acc, nullptr, Xg, row0, wbuf + OFF_WHT + 1 * 65536, w, lo, hi);
#pragma unroll
  for (int tc = 0; tc < 4; ++tc) {
    const int col = w * 64 + tc * 16 + lo;
    const float bs = b_lstm[1 * 256 + col];
#pragma unroll
    for (int rb = 0; rb < 4; ++rb)
#pragma unroll
      for (int i = 0; i < 4; ++i) {
        const int ri = rb * 16 + hi * 4 + i;
        const float cdec = cell[(size_t)lnd[ri] * 256 + col] * decv[ri];
        const float cn = lloadf(bufB, ri, col * 2) + sigm_f(acc[rb][tc][i] + bs) * cdec;
        lstore(bufB, ri, col * 2, (bf16_t)cn);
      }
  }
  // gate "o": c_new = carry; h = sigm(pre)*tanh(c_new); outputs + score dot
  zacc(acc);
  gacc<true >(acc, bufA, nullptr, 0, wbuf + OFF_WXT + 3 * 65536, w, lo, hi);
  gacc<false>(acc, nullptr, Xg, row0, wbuf + OFF_WHT + 3 * 65536, w, lo, hi);
  {
    float dp[4][4] = {};
#pragma unroll
    for (int tc = 0; tc < 4; ++tc) {
      const int col = w * 64 + tc * 16 + lo;
      const float bs = b_lstm[3 * 256 + col];
      const float wo = w_out[col];
#pragma unroll
      for (int rb = 0; rb < 4; ++rb)
#pragma unroll
        for (int i = 0; i < 4; ++i) {
          const int ri = rb * 16 + hi * 4 + i;
          const int m = leid[ri];
          const float cn = lloadf(bufB, ri, col * 2);
          const float hn = sigm_f(acc[rb][tc][i] + bs) * tanh_f(cn);
          if (m >= 0) {
            outH[(size_t)m * 256 + col] = hn;
            outC[(size_t)m * 256 + col] = cn;
          }
          dp[rb][i] += hn * wo;
        }
    }
#pragma unroll
    for (int rb = 0; rb < 4; ++rb)
#pragma unroll
      for (int i = 0; i < 4; ++i) {
        float d = dp[rb][i];
        d += __shfl_xor(d, 1); d += __shfl_xor(d, 2);
        d += __shfl_xor(d, 4); d += __shfl_xor(d, 8);
        if (lo == 0) atomicAdd(&sdot[rb * 16 + hi * 4 + i], d);
      }
  }
  __syncthreads();
  if (tid < TROWS) {
    const int m = leid[tid];
    if (m >= 0) outS[m] = sigm_f(sdot[tid] + b_out[0]);
  }
}

// ---------------------------------------------------------------------------
extern "C" void kernel_launch(void* const* d_in, const int* in_sizes, int n_in,
                              void* d_out, int out_size, void* d_ws, size_t ws_size,
                              hipStream_t stream)
{
  const int*   src     = (const int*)d_in[0];
  const int*   dst     = (const int*)d_in[1];
  const int*   etype   = (const int*)d_in[2];
  const float* dt      = (const float*)d_in[3];
  const float* hid     = (const float*)d_in[4];
  const float* cell    = (const float*)d_in[5];
  const float* W1s     = (const float*)d_in[6];
  const float* b1s     = (const float*)d_in[7];
  const float* W2s     = (const float*)d_in[8];
  const float* b2s     = (const float*)d_in[9];
  const float* W1g     = (const float*)d_in[10];
  const float* b1g     = (const float*)d_in[11];
  const float* W2g     = (const float*)d_in[12];
  const float* b2g     = (const float*)d_in[13];
  const float* p_w     = (const float*)d_in[14];
  const float* p_b     = (const float*)d_in[15];
  const float* q_w     = (const float*)d_in[16];
  const float* q_b     = (const float*)d_in[17];
  const float* Ws_w    = (const float*)d_in[18];
  const float* Ws_b    = (const float*)d_in[19];
  const float* Wg_w    = (const float*)d_in[20];
  const float* Wg_b    = (const float*)d_in[21];
  const float* Wx      = (const float*)d_in[22];
  const float* Wh      = (const float*)d_in[23];
  const float* b_lstm  = (const float*)d_in[24];
  const float* w_out   = (const float*)d_in[25];
  const float* b_out   = (const float*)d_in[26];
  const float* decay_w = (const float*)d_in[27];
  (void)in_sizes; (void)n_in; (void)out_size; (void)ws_size;

  char* p = (char*)d_ws;
  auto alloc = [&](size_t bytes) { char* r = p; p += (bytes + 255) & ~(size_t)255; return r; };
  const size_t SB = (size_t)S_TOP * 256 * sizeof(bf16_t);
  bf16_t* wbuf = (bf16_t*)alloc(WBUF_ELEMS * sizeof(bf16_t));
  bf16_t* Xs   = (bf16_t*)alloc(SB);
  bf16_t* Xg   = (bf16_t*)alloc(SB);
  int*    eid  = (int*)alloc(S_TOP * 4);
  int*    srcn = (int*)alloc(S_TOP * 4);
  int*    dstn = (int*)alloc(S_TOP * 4);
  float*  dts  = (float*)alloc(S_TOP * 4);
  int*    cnt  = (int*)alloc(256);

  float* outS = (float*)d_out;
  float* outH = outS + M_EDGES;
  float* outC = outH + (size_t)M_EDGES * 256;

  k_init<<<384, 256, 0, stream>>>(W1s, W2s, W1g, W2g, Ws_w, Wg_w, Wx, Wh,
                                  wbuf, eid, srcn, dstn, dts, cnt);
  k_slots<<<M_EDGES / 256, 256, 0, stream>>>(etype, src, dst, dt, cnt, eid, srcn, dstn, dts);
  k_gather<<<S_TOP / 4, 256, 0, stream>>>(hid, srcn, dstn, Xs, Xg);
  k_mega<<<GRID_MEGA, 256, 0, stream>>>(Xs, Xg, wbuf,
      b1s, b2s, b1g, b2g, p_w, p_b, q_w, q_b, Ws_b, Wg_b,
      b_lstm, w_out, b_out, decay_w, cell, cnt, eid, dstn, dts,
      outS, outH, outC);
}

// Round 8
// 687.362 us; speedup vs baseline: 1.5621x; 1.0170x over previous
//
#include <hip/hip_runtime.h>

// ---------------------------------------------------------------------------
// DyHetGNN forward, fused mega-kernel with FRAGMENT-ORDERED operands.
// All global MFMA operands (weights, Xs, Xg) are stored in 1KB lane-ordered
// fragment blocks: lane l reads its 16B at base + l*16 (fully coalesced).
// B block (n0,K0): elem [n0+lo][K0+hi*8+j] at ((n0>>4)*8+(K0>>5))*512+(hi*16+lo)*8+j
// A block (t,rb,K0): elem [t*64+rb*16+lo][K0+hi*8+j] at ((t*4+rb)*8+(K0>>5))*512+(hi*16+lo)*8+j
// Slots: etype0 rows [0,cnt0), etype1 rows [S_TOP-cnt1, S_TOP); pads garbage.
// ---------------------------------------------------------------------------

#define M_EDGES 32768
#define S_TOP   32896          // M + 128, multiple of 128 (and of 64)
#define TROWS   64
#define GRID_MEGA (S_TOP / TROWS)   // 514

typedef __bf16 bf16_t;
typedef __bf16 bf16x8 __attribute__((ext_vector_type(8)));
typedef float  f32x4  __attribute__((ext_vector_type(4)));

// weight buffer segment offsets (bf16 elements), fragment-ordered
#define OFF_W1ST 0
#define OFF_W2ST 131072
#define OFF_W1GT 262144
#define OFF_W2GT 393216
#define OFF_WST  524288
#define OFF_WGT  589824
#define OFF_WXT  655360
#define OFF_WHT  917504
#define WBUF_ELEMS 1179648

__device__ __forceinline__ float sigm_f(float x) { return 1.f / (1.f + __expf(-x)); }
__device__ __forceinline__ float tanh_f(float x) {
  x = fminf(fmaxf(x, -15.f), 15.f);
  float e = __expf(2.f * x);
  return (e - 1.f) / (e + 1.f);
}

// frag offset helpers (bf16-element offsets)
__device__ __forceinline__ int bfrag_off(int n, int k) {   // within one 256x256 matrix
  return ((n >> 4) * 8 + (k >> 5)) * 512 + ((((k >> 3) & 3) * 16 + (n & 15)) * 8) + (k & 7);
}

// ---------------- prep: weight transpose/cast to fragment layout ----------------
__global__ __launch_bounds__(256)
void k_init(const float* __restrict__ W1s, const float* __restrict__ W2s,
            const float* __restrict__ W1g, const float* __restrict__ W2g,
            const float* __restrict__ Wsw, const float* __restrict__ Wgw,
            const float* __restrict__ Wx,  const float* __restrict__ Wh,
            bf16_t* __restrict__ wbuf, int* __restrict__ eid,
            int* __restrict__ srcn, int* __restrict__ dstn,
            float* __restrict__ dts, int* __restrict__ cnt)
{
  const int b = blockIdx.x, tid = threadIdx.x;
  if (b < 256) {                       // transposed matrices: src is [k][n]
    const float* src; bf16_t* fbase; int C_in, n0, k0, nbase;
    if (b < 128) {
      const int grp = b >> 5, e = (b >> 4) & 1, t16 = b & 15;
      const float* bases[4] = {W1s, W2s, W1g, W2g};
      src = bases[grp] + e * 65536;
      fbase = wbuf + grp * 131072 + e * 65536;
      C_in = 256; n0 = (t16 >> 2) * 64; k0 = (t16 & 3) * 64; nbase = n0;
    } else {
      const int b2 = b - 128, mat = b2 >> 6, t64 = b2 & 63;
      src = mat ? Wh : Wx;
      C_in = 1024; n0 = (t64 >> 2) * 64; k0 = (t64 & 3) * 64;
      const int gate = n0 >> 8;
      fbase = wbuf + OFF_WXT + mat * 262144 + gate * 65536;
      nbase = n0 & 255;
    }
    __shared__ float tile[64][65];     // tile[k_local][n_local]
    const int r = tid >> 2, cg = (tid & 3) * 16;
#pragma unroll
    for (int j = 0; j < 4; ++j) {
      float4 v = *(const float4*)(src + (k0 + r) * C_in + n0 + cg + 4 * j);
      tile[r][cg + 4 * j + 0] = v.x;
      tile[r][cg + 4 * j + 1] = v.y;
      tile[r][cg + 4 * j + 2] = v.z;
      tile[r][cg + 4 * j + 3] = v.w;
    }
    __syncthreads();
    const int n_local = tid >> 2;
#pragma unroll
    for (int gp = 0; gp < 2; ++gp) {
      const int g = (tid & 3) * 2 + gp;          // 8-elem k-group, k_local=g*8..+7
      bf16x8 v;
#pragma unroll
      for (int jj = 0; jj < 8; ++jj) v[jj] = (bf16_t)tile[g * 8 + jj][n_local];
      const int n = nbase + n_local, k = k0 + g * 8;
      *(bf16x8*)(fbase + bfrag_off(n, k)) = v;
    }
  } else {                             // direct [n][k] matrices + defaults
    const int flat = (b - 256) * 256 + tid;      // 0..32767 over 128 blocks
    if (flat < 16384) {
      const int matsel = flat >> 13;             // 0: Ws_w, 1: Wg_w
      const int gi = flat & 8191;
      const float* srcw = matsel ? Wgw : Wsw;
      bf16_t* fb = wbuf + (matsel ? OFF_WGT : OFF_WST);
      const int n = gi >> 5, kg = gi & 31;
      float4 v0 = *(const float4*)(srcw + n * 256 + kg * 8);
      float4 v1 = *(const float4*)(srcw + n * 256 + kg * 8 + 4);
      bf16x8 v;
      v[0] = (bf16_t)v0.x; v[1] = (bf16_t)v0.y; v[2] = (bf16_t)v0.z; v[3] = (bf16_t)v0.w;
      v[4] = (bf16_t)v1.x; v[5] = (bf16_t)v1.y; v[6] = (bf16_t)v1.z; v[7] = (bf16_t)v1.w;
      *(bf16x8*)(fb + bfrag_off(n, kg * 8)) = v;
    }
    for (int i = flat; i < S_TOP; i += 32768) {
      eid[i] = -1; srcn[i] = 0; dstn[i] = 0; dts[i] = 0.f;
    }
    if (flat < 2) cnt[flat] = 0;
  }
}

// ---------------- slot assignment (wave-aggregated atomics) ----------------
__global__ __launch_bounds__(256)
void k_slots(const int* __restrict__ etype, const int* __restrict__ src,
             const int* __restrict__ dst, const float* __restrict__ dt,
             int* __restrict__ cnt, int* __restrict__ eid, int* __restrict__ srcn,
             int* __restrict__ dstn, float* __restrict__ dts)
{
  const int m = blockIdx.x * 256 + threadIdx.x;
  const int lane = threadIdx.x & 63;
  const int e = etype[m];
  const unsigned long long b0 = __ballot(e == 0);
  const unsigned long long lt = (1ull << lane) - 1;
  const int c0 = __popcll(b0);
  int a0 = 0, a1 = 0;
  if (lane == 0) {
    a0 = atomicAdd(&cnt[0], c0);
    a1 = atomicAdd(&cnt[1], 64 - c0);
  }
  a0 = __shfl(a0, 0);
  a1 = __shfl(a1, 0);
  const int pos = (e == 0) ? (a0 + __popcll(b0 & lt))
                           : (a1 + __popcll(~b0 & lt));
  const int s = (e == 0) ? pos : (S_TOP - 1 - pos);
  eid[s] = m; srcn[s] = src[m]; dstn[s] = dst[m]; dts[s] = dt[m];
}

// ---------------- gather hid rows -> A-fragment-ordered bf16 ----------------
__global__ __launch_bounds__(256)
void k_gather(const float* __restrict__ hid, const int* __restrict__ srcn,
              const int* __restrict__ dstn, bf16_t* __restrict__ Xs,
              bf16_t* __restrict__ Xg)
{
  const int s = blockIdx.x * 8 + (threadIdx.x >> 5);
  const int kg = threadIdx.x & 31;               // 8-elem k-group
  const int ns = srcn[s], ng = dstn[s];
  const int t = s >> 6, r = s & 63;
  const int off = ((t * 4 + (r >> 4)) * 8 + (kg >> 2)) * 512 + (((kg & 3) * 16 + (r & 15)) * 8);
  float4 a0 = *(const float4*)(hid + (size_t)ns * 256 + kg * 8);
  float4 a1 = *(const float4*)(hid + (size_t)ns * 256 + kg * 8 + 4);
  bf16x8 v;
  v[0] = (bf16_t)a0.x; v[1] = (bf16_t)a0.y; v[2] = (bf16_t)a0.z; v[3] = (bf16_t)a0.w;
  v[4] = (bf16_t)a1.x; v[5] = (bf16_t)a1.y; v[6] = (bf16_t)a1.z; v[7] = (bf16_t)a1.w;
  *(bf16x8*)(Xs + off) = v;
  float4 g0 = *(const float4*)(hid + (size_t)ng * 256 + kg * 8);
  float4 g1 = *(const float4*)(hid + (size_t)ng * 256 + kg * 8 + 4);
  v[0] = (bf16_t)g0.x; v[1] = (bf16_t)g0.y; v[2] = (bf16_t)g0.z; v[3] = (bf16_t)g0.w;
  v[4] = (bf16_t)g1.x; v[5] = (bf16_t)g1.y; v[6] = (bf16_t)g1.z; v[7] = (bf16_t)g1.w;
  *(bf16x8*)(Xg + off) = v;
}

// ---------------- mega-kernel helpers ----------------
// LDS tile [64][256] bf16, row stride 512B, XOR-swizzled within row (16B units)
__device__ __forceinline__ bf16x8 lfrag(const unsigned short* buf, int row, int kbyte) {
  return *(const bf16x8*)((const char*)buf + row * 512 + (kbyte ^ ((row & 7) << 4)));
}
__device__ __forceinline__ void lstore(unsigned short* buf, int row, int colbyte, bf16_t v) {
  *(bf16_t*)((char*)buf + row * 512 + (colbyte ^ ((row & 7) << 4))) = v;
}
__device__ __forceinline__ float lloadf(const unsigned short* buf, int row, int colbyte) {
  return (float)*(const bf16_t*)((const char*)buf + row * 512 + (colbyte ^ ((row & 7) << 4)));
}
__device__ __forceinline__ void zacc(f32x4 (&acc)[4][4]) {
  const f32x4 z = {0.f, 0.f, 0.f, 0.f};
#pragma unroll
  for (int a = 0; a < 4; ++a)
#pragma unroll
    for (int b = 0; b < 4; ++b) acc[a][b] = z;
}
// one K=256 GEMM-accumulate over a 64-row tile; this wave's 64-col slab.
// A from LDS tile (LDSA) or fragment-ordered global tile gAt; W fragment-ordered.
template<bool LDSA>
__device__ __forceinline__ void gacc(f32x4 (&acc)[4][4], const unsigned short* lb,
                                     const bf16_t* gAt, const bf16_t* Wf,
                                     int w, int lane, int lo, int hi)
{
#pragma unroll
  for (int c = 0; c < 4; ++c)
#pragma unroll
    for (int ks = 0; ks < 2; ++ks) {
      const int kb = c * 2 + ks;
      bf16x8 af[4];
#pragma unroll
      for (int rb = 0; rb < 4; ++rb) {
        if constexpr (LDSA) af[rb] = lfrag(lb, rb * 16 + lo, (c * 64 + ks * 32 + hi * 8) * 2);
        else                af[rb] = *(const bf16x8*)(gAt + (rb * 8 + kb) * 512 + lane * 8);
      }
#pragma unroll
      for (int tc = 0; tc < 4; ++tc) {
        bf16x8 bfv = *(const bf16x8*)(Wf + ((w * 4 + tc) * 8 + kb) * 512 + lane * 8);
#pragma unroll
        for (int rb = 0; rb < 4; ++rb)
          acc[rb][tc] = __builtin_amdgcn_mfma_f32_16x16x32_bf16(af[rb], bfv, acc[rb][tc], 0, 0, 0);
      }
    }
}

// ---------------- the fused chain kernel ----------------
__global__ __launch_bounds__(256, 2)
void k_mega(const bf16_t* __restrict__ Xs, const bf16_t* __restrict__ Xg,
            const bf16_t* __restrict__ wbuf,
            const float* __restrict__ b1s, const float* __restrict__ b2s,
            const float* __restrict__ b1g, const float* __restrict__ b2g,
            const float* __restrict__ p_w, const float* __restrict__ p_b,
            const float* __restrict__ q_w, const float* __restrict__ q_b,
            const float* __restrict__ Wsb, const float* __restrict__ Wgb,
            const float* __restrict__ b_lstm, const float* __restrict__ w_out,
            const float* __restrict__ b_out, const float* __restrict__ decay_w,
            const float* __restrict__ cell, const int* __restrict__ cnt,
            const int* __restrict__ eid, const int* __restrict__ dstn,
            const float* __restrict__ dts,
            float* __restrict__ outS, float* __restrict__ outH, float* __restrict__ outC)
{
  const int tid = threadIdx.x;
  const int w = tid >> 6, lane = tid & 63, lo = lane & 15, hi = lane >> 4;
  const int row0 = blockIdx.x * TROWS;
  const int cnt0 = cnt[0], cnt1 = cnt[1];
  const int cnt0r = (cnt0 + TROWS - 1) & ~(TROWS - 1);
  const int v1 = S_TOP - cnt1;
  if (row0 >= cnt0r && row0 + TROWS <= v1) return;   // fully-dead block
  const int e = (row0 < cnt0r) ? 0 : 1;

  const bf16_t* XsT = Xs + (row0 >> 6) * 16384;   // this block's A-frag tiles
  const bf16_t* XgT = Xg + (row0 >> 6) * 16384;

  __shared__ unsigned short bufA[TROWS * 256];   // 32 KiB
  __shared__ unsigned short bufB[TROWS * 256];   // 32 KiB (msg_s -> T -> carry)
  __shared__ float ps[TROWS], qs[TROWS], aa[TROWS], sdot[TROWS], decv[TROWS];
  __shared__ int leid[TROWS], lnd[TROWS];

  if (tid < TROWS) {
    const int r = row0 + tid;
    ps[tid] = 0.f; qs[tid] = 0.f; sdot[tid] = 0.f;
    leid[tid] = eid[r]; lnd[tid] = dstn[r];
    decv[tid] = __expf(-fabsf(decay_w[0]) * dts[r]);
  }

  f32x4 acc[4][4];   // the ONLY 64-float register array ever live

  // ---- P1: h1s = relu(Xs @ W1s[e] + b1s[e]) -> bufA
  zacc(acc);
  gacc<false>(acc, nullptr, XsT, wbuf + OFF_W1ST + e * 65536, w, lane, lo, hi);
  {
    const float* bias = b1s + e * 256;
#pragma unroll
    for (int tc = 0; tc < 4; ++tc) {
      const int col = w * 64 + tc * 16 + lo;
      const float bs = bias[col];
#pragma unroll
      for (int rb = 0; rb < 4; ++rb)
#pragma unroll
        for (int i = 0; i < 4; ++i)
          lstore(bufA, rb * 16 + hi * 4 + i, col * 2, (bf16_t)fmaxf(acc[rb][tc][i] + bs, 0.f));
    }
  }
  __syncthreads();

  // ---- P2: msg_s = bufA @ W2s[e] + b2s[e] -> bufB ; ps += msg_s . p_w
  zacc(acc);
  gacc<true>(acc, bufA, nullptr, wbuf + OFF_W2ST + e * 65536, w, lane, lo, hi);
  {
    const float* bias = b2s + e * 256;
    float dp[4][4] = {};
#pragma unroll
    for (int tc = 0; tc < 4; ++tc) {
      const int col = w * 64 + tc * 16 + lo;
      const float bs = bias[col], pw = p_w[col];
#pragma unroll
      for (int rb = 0; rb < 4; ++rb)
#pragma unroll
        for (int i = 0; i < 4; ++i) {
          const float v = acc[rb][tc][i] + bs;
          lstore(bufB, rb * 16 + hi * 4 + i, col * 2, (bf16_t)v);
          dp[rb][i] += v * pw;
        }
    }
#pragma unroll
    for (int rb = 0; rb < 4; ++rb)
#pragma unroll
      for (int i = 0; i < 4; ++i) {
        float d = dp[rb][i];
        d += __shfl_xor(d, 1); d += __shfl_xor(d, 2);
        d += __shfl_xor(d, 4); d += __shfl_xor(d, 8);
        if (lo == 0) atomicAdd(&ps[rb * 16 + hi * 4 + i], d);
      }
  }
  __syncthreads();

  // ---- P3: T = bufB @ Ws^T + Ws_b  -> stored back IN-PLACE into bufB (bf16)
  zacc(acc);
  gacc<true>(acc, bufB, nullptr, wbuf + OFF_WST, w, lane, lo, hi);
#pragma unroll
  for (int tc = 0; tc < 4; ++tc) {
    const float bs = Wsb[w * 64 + tc * 16 + lo];
#pragma unroll
    for (int rb = 0; rb < 4; ++rb)
#pragma unroll
      for (int i = 0; i < 4; ++i) acc[rb][tc][i] += bs;
  }
  __syncthreads();                      // everyone done READING bufB (msg_s)
#pragma unroll
  for (int tc = 0; tc < 4; ++tc) {
    const int col = w * 64 + tc * 16 + lo;
#pragma unroll
    for (int rb = 0; rb < 4; ++rb)
#pragma unroll
      for (int i = 0; i < 4; ++i)
        lstore(bufB, rb * 16 + hi * 4 + i, col * 2, (bf16_t)acc[rb][tc][i]);
  }
  __syncthreads();

  // ---- P4: h1g = relu(Xg @ W1g[e] + b1g[e]) -> bufA
  zacc(acc);
  gacc<false>(acc, nullptr, XgT, wbuf + OFF_W1GT + e * 65536, w, lane, lo, hi);
  {
    const float* bias = b1g + e * 256;
#pragma unroll
    for (int tc = 0; tc < 4; ++tc) {
      const int col = w * 64 + tc * 16 + lo;
      const float bs = bias[col];
#pragma unroll
      for (int rb = 0; rb < 4; ++rb)
#pragma unroll
        for (int i = 0; i < 4; ++i)
          lstore(bufA, rb * 16 + hi * 4 + i, col * 2, (bf16_t)fmaxf(acc[rb][tc][i] + bs, 0.f));
    }
  }
  __syncthreads();

  // ---- P5: msg_g = bufA @ W2g[e] + b2g[e] -> IN-PLACE into bufA ; qs-dot
  zacc(acc);
  gacc<true>(acc, bufA, nullptr, wbuf + OFF_W2GT + e * 65536, w, lane, lo, hi);
  {
    const float* bias = b2g + e * 256;
    float dp[4][4] = {};
#pragma unroll
    for (int tc = 0; tc < 4; ++tc) {
      const int col = w * 64 + tc * 16 + lo;
      const float bs = bias[col], qw = q_w[col];
#pragma unroll
      for (int rb = 0; rb < 4; ++rb)
#pragma unroll
        for (int i = 0; i < 4; ++i) {
          acc[rb][tc][i] += bs;
          dp[rb][i] += acc[rb][tc][i] * qw;
        }
    }
#pragma unroll
    for (int rb = 0; rb < 4; ++rb)
#pragma unroll
      for (int i = 0; i < 4; ++i) {
        float d = dp[rb][i];
        d += __shfl_xor(d, 1); d += __shfl_xor(d, 2);
        d += __shfl_xor(d, 4); d += __shfl_xor(d, 8);
        if (lo == 0) atomicAdd(&qs[rb * 16 + hi * 4 + i], d);
      }
  }
  __syncthreads();                      // everyone done READING bufA (h1g)
#pragma unroll
  for (int tc = 0; tc < 4; ++tc) {
    const int col = w * 64 + tc * 16 + lo;
#pragma unroll
    for (int rb = 0; rb < 4; ++rb)
#pragma unroll
      for (int i = 0; i < 4; ++i)
        lstore(bufA, rb * 16 + hi * 4 + i, col * 2, (bf16_t)acc[rb][tc][i]);
  }
  __syncthreads();

  // ---- a = sigmoid(ps + qs + p_b + q_b)
  if (tid < TROWS) aa[tid] = sigm_f(ps[tid] + qs[tid] + p_b[0] + q_b[0]);
  __syncthreads();

  // ---- P6: G = bufA @ Wg^T + Wg_b ; X = a*T + (1-a)*G -> IN-PLACE bufA
  zacc(acc);
  gacc<true>(acc, bufA, nullptr, wbuf + OFF_WGT, w, lane, lo, hi);
#pragma unroll
  for (int tc = 0; tc < 4; ++tc) {
    const int col = w * 64 + tc * 16 + lo;
    const float bs = Wgb[col];
#pragma unroll
    for (int rb = 0; rb < 4; ++rb)
#pragma unroll
      for (int i = 0; i < 4; ++i) {
        const int ri = rb * 16 + hi * 4 + i;
        const float av = aa[ri];
        const float tv = lloadf(bufB, ri, col * 2);   // T
        acc[rb][tc][i] = av * tv + (1.f - av) * (acc[rb][tc][i] + bs);
      }
  }
  __syncthreads();                      // reads of bufA (msg_g) + bufB (T) done
#pragma unroll
  for (int tc = 0; tc < 4; ++tc) {
    const int col = w * 64 + tc * 16 + lo;
#pragma unroll
    for (int rb = 0; rb < 4; ++rb)
#pragma unroll
      for (int i = 0; i < 4; ++i)
        lstore(bufA, rb * 16 + hi * 4 + i, col * 2, (bf16_t)acc[rb][tc][i]);
  }
  __syncthreads();

  // ---- gates (X = bufA stays pinned; carry lives bf16 in bufB, thread-private
  //      elementwise slots -> no barriers needed between gates).
  // gate "g": carry = tanh(pre)
  zacc(acc);
  gacc<true >(acc, bufA, nullptr, wbuf + OFF_WXT + 2 * 65536, w, lane, lo, hi);
  gacc<false>(acc, nullptr, XgT, wbuf + OFF_WHT + 2 * 65536, w, lane, lo, hi);
#pragma unroll
  for (int tc = 0; tc < 4; ++tc) {
    const int col = w * 64 + tc * 16 + lo;
    const float bs = b_lstm[2 * 256 + col];
#pragma unroll
    for (int rb = 0; rb < 4; ++rb)
#pragma unroll
      for (int i = 0; i < 4; ++i)
        lstore(bufB, rb * 16 + hi * 4 + i, col * 2, (bf16_t)tanh_f(acc[rb][tc][i] + bs));
  }
  // gate "i": carry *= sigm(pre)
  zacc(acc);
  gacc<true >(acc, bufA, nullptr, wbuf + OFF_WXT + 0 * 65536, w, lane, lo, hi);
  gacc<false>(acc, nullptr, XgT, wbuf + OFF_WHT + 0 * 65536, w, lane, lo, hi);
#pragma unroll
  for (int tc = 0; tc < 4; ++tc) {
    const int col = w * 64 + tc * 16 + lo;
    const float bs = b_lstm[0 * 256 + col];
#pragma unroll
    for (int rb = 0; rb < 4; ++rb)
#pragma unroll
      for (int i = 0; i < 4; ++i) {
        const int ri = rb * 16 + hi * 4 + i;
        const float c1 = lloadf(bufB, ri, col * 2) * sigm_f(acc[rb][tc][i] + bs);
        lstore(bufB, ri, col * 2, (bf16_t)c1);
      }
  }
  // gate "f": carry += sigm(pre) * c_dec
  zacc(acc);
  gacc<true >(acc, bufA, nullptr, wbuf + OFF_WXT + 1 * 65536, w, lane, lo, hi);
  gacc<false>(acc, nullptr, XgT, wbuf + OFF_WHT + 1 * 65536, w, lane, lo, hi);
#pragma unroll
  for (int tc = 0; tc < 4; ++tc) {
    const int col = w * 64 + tc * 16 + lo;
    const float bs = b_lstm[1 * 256 + col];
#pragma unroll
    for (int rb = 0; rb < 4; ++rb)
#pragma unroll
      for (int i = 0; i < 4; ++i) {
        const int ri = rb * 16 + hi * 4 + i;
        const float cdec = cell[(size_t)lnd[ri] * 256 + col] * decv[ri];
        const float cn = lloadf(bufB, ri, col * 2) + sigm_f(acc[rb][tc][i] + bs) * cdec;
        lstore(bufB, ri, col * 2, (bf16_t)cn);
      }
  }
  // gate "o": c_new = carry; h = sigm(pre)*tanh(c_new); outputs + score dot
  zacc(acc);
  gacc<true >(acc, bufA, nullptr, wbuf + OFF_WXT + 3 * 65536, w, lane, lo, hi);
  gacc<false>(acc, nullptr, XgT, wbuf + OFF_WHT + 3 * 65536, w, lane, lo, hi);
  {
    float dp[4][4] = {};
#pragma unroll
    for (int tc = 0; tc < 4; ++tc) {
      const int col = w * 64 + tc * 16 + lo;
      const float bs = b_lstm[3 * 256 + col];
      const float wo = w_out[col];
#pragma unroll
      for (int rb = 0; rb < 4; ++rb)
#pragma unroll
        for (int i = 0; i < 4; ++i) {
          const int ri = rb * 16 + hi * 4 + i;
          const int m = leid[ri];
          const float cn = lloadf(bufB, ri, col * 2);
          const float hn = sigm_f(acc[rb][tc][i] + bs) * tanh_f(cn);
          if (m >= 0) {
            outH[(size_t)m * 256 + col] = hn;
            outC[(size_t)m * 256 + col] = cn;
          }
          dp[rb][i] += hn * wo;
        }
    }
#pragma unroll
    for (int rb = 0; rb < 4; ++rb)
#pragma unroll
      for (int i = 0; i < 4; ++i) {
        float d = dp[rb][i];
        d += __shfl_xor(d, 1); d += __shfl_xor(d, 2);
        d += __shfl_xor(d, 4); d += __shfl_xor(d, 8);
        if (lo == 0) atomicAdd(&sdot[rb * 16 + hi * 4 + i], d);
      }
  }
  __syncthreads();
  if (tid < TROWS) {
    const int m = leid[tid];
    if (m >= 0) outS[m] = sigm_f(sdot[tid] + b_out[0]);
  }
}

// ---------------------------------------------------------------------------
extern "C" void kernel_launch(void* const* d_in, const int* in_sizes, int n_in,
                              void* d_out, int out_size, void* d_ws, size_t ws_size,
                              hipStream_t stream)
{
  const int*   src     = (const int*)d_in[0];
  const int*   dst     = (const int*)d_in[1];
  const int*   etype   = (const int*)d_in[2];
  const float* dt      = (const float*)d_in[3];
  const float* hid     = (const float*)d_in[4];
  const float* cell    = (const float*)d_in[5];
  const float* W1s     = (const float*)d_in[6];
  const float* b1s     = (const float*)d_in[7];
  const float* W2s     = (const float*)d_in[8];
  const float* b2s     = (const float*)d_in[9];
  const float* W1g     = (const float*)d_in[10];
  const float* b1g     = (const float*)d_in[11];
  const float* W2g     = (const float*)d_in[12];
  const float* b2g     = (const float*)d_in[13];
  const float* p_w     = (const float*)d_in[14];
  const float* p_b     = (const float*)d_in[15];
  const float* q_w     = (const float*)d_in[16];
  const float* q_b     = (const float*)d_in[17];
  const float* Ws_w    = (const float*)d_in[18];
  const float* Ws_b    = (const float*)d_in[19];
  const float* Wg_w    = (const float*)d_in[20];
  const float* Wg_b    = (const float*)d_in[21];
  const float* Wx      = (const float*)d_in[22];
  const float* Wh      = (const float*)d_in[23];
  const float* b_lstm  = (const float*)d_in[24];
  const float* w_out   = (const float*)d_in[25];
  const float* b_out   = (const float*)d_in[26];
  const float* decay_w = (const float*)d_in[27];
  (void)in_sizes; (void)n_in; (void)out_size; (void)ws_size;

  char* p = (char*)d_ws;
  auto alloc = [&](size_t bytes) { char* r = p; p += (bytes + 255) & ~(size_t)255; return r; };
  const size_t SB = (size_t)S_TOP * 256 * sizeof(bf16_t);
  bf16_t* wbuf = (bf16_t*)alloc(WBUF_ELEMS * sizeof(bf16_t));
  bf16_t* Xs   = (bf16_t*)alloc(SB);
  bf16_t* Xg   = (bf16_t*)alloc(SB);
  int*    eid  = (int*)alloc(S_TOP * 4);
  int*    srcn = (int*)alloc(S_TOP * 4);
  int*    dstn = (int*)alloc(S_TOP * 4);
  float*  dts  = (float*)alloc(S_TOP * 4);
  int*    cnt  = (int*)alloc(256);

  float* outS = (float*)d_out;
  float* outH = outS + M_EDGES;
  float* outC = outH + (size_t)M_EDGES * 256;

  k_init<<<384, 256, 0, stream>>>(W1s, W2s, W1g, W2g, Ws_w, Wg_w, Wx, Wh,
                                  wbuf, eid, srcn, dstn, dts, cnt);
  k_slots<<<M_EDGES / 256, 256, 0, stream>>>(etype, src, dst, dt, cnt, eid, srcn, dstn, dts);
  k_gather<<<S_TOP / 8, 256, 0, stream>>>(hid, srcn, dstn, Xs, Xg);
  k_mega<<<GRID_MEGA, 256, 0, stream>>>(Xs, Xg, wbuf,
      b1s, b2s, b1g, b2g, p_w, p_b, q_w, q_b, Ws_b, Wg_b,
      b_lstm, w_out, b_out, decay_w, cell, cnt, eid, dstn, dts,
      outS, outH, outC);
}